// Round 6
// baseline (401.593 us; speedup 1.0000x reference)
//
#include <hip/hip_runtime.h>
#include <stdint.h>

#define N_NODES 100000
#define N_EDGES 1600000
#define FDIM 128
#define NREL 50
#define BN_EPS 1e-3f
#define N_PAD 100096
#define NBUCK 782          // ceil(N_NODES / 128)
#define EPB 8192           // edges per sort block
#define NBLK 196           // ceil(N_EDGES / EPB)
#define NSEG 4             // ceil(NBLK / 64)
#define SLACK 384          // max pad per bucket: 128 rows * 3
#define HBLK 6250          // N*32 / 512

typedef short short8_t __attribute__((ext_vector_type(8)));
typedef float f32x4_t __attribute__((ext_vector_type(4)));

__device__ __forceinline__ uint32_t f2bf(float f) {
    union { float f; uint32_t u; } v; v.f = f;
    uint32_t u = v.u;
    return (u + 0x7FFFu + ((u >> 16) & 1u)) >> 16;   // RNE, inputs finite
}
__device__ __forceinline__ float bflo(uint32_t p) {
    union { uint32_t u; float f; } v; v.u = p << 16; return v.f;
}
__device__ __forceinline__ float bfhi(uint32_t p) {
    union { uint32_t u; float f; } v; v.u = p & 0xFFFF0000u; return v.f;
}

// ---- fused prologue: blocks [0,NBLK) = bucket histogram; block NBLK = WT cast;
// blocks (NBLK, NBLK+HBLK] = BN h (scale/shift computed per-thread, params L2-hot).
__global__ __launch_bounds__(512) void pre_kernel(
        const float* __restrict__ x, const int* __restrict__ rows,
        const float* __restrict__ gamma, const float* __restrict__ beta,
        const float* __restrict__ mean, const float* __restrict__ var,
        const float* __restrict__ W,
        uint2* __restrict__ h, int* __restrict__ bhist, uint16_t* __restrict__ WT) {
    __shared__ int lh[NBUCK];
    int b = blockIdx.x, t = threadIdx.x;
    if (b < NBLK) {
        for (int i = t; i < NBUCK; i += 512) lh[i] = 0;
        __syncthreads();
        int e0 = b * EPB, e1 = min(e0 + EPB, N_EDGES);
        for (int e = e0 + t; e < e1; e += 512)
            atomicAdd(&lh[rows[e] >> 7], 1);
        __syncthreads();
        for (int i = t; i < NBUCK; i += 512) bhist[(size_t)i * NBLK + b] = lh[i];
    } else if (b == NBLK) {
        for (int idx = t; idx < FDIM * FDIM; idx += 512) {
            int f = idx >> 7, k = idx & 127;
            WT[idx] = (uint16_t)f2bf(W[k * FDIM + f]);   // WT[f][k]
        }
    } else {
        int i4 = (b - NBLK - 1) * 512 + t;     // 0 .. N*32-1 exactly
        int cg = (i4 & 31) * 4;
        float4 xv = ((const float4*)x)[i4];
        float4 g4 = *(const float4*)(gamma + cg);
        float4 b4 = *(const float4*)(beta + cg);
        float4 m4 = *(const float4*)(mean + cg);
        float4 v4 = *(const float4*)(var + cg);
        float s0 = g4.x * rsqrtf(v4.x + BN_EPS);
        float s1 = g4.y * rsqrtf(v4.y + BN_EPS);
        float s2 = g4.z * rsqrtf(v4.z + BN_EPS);
        float s3 = g4.w * rsqrtf(v4.w + BN_EPS);
        float h0 = (xv.x - m4.x) * s0 + b4.x;
        float h1 = (xv.y - m4.y) * s1 + b4.y;
        float h2 = (xv.z - m4.z) * s2 + b4.z;
        float h3 = (xv.w - m4.w) * s3 + b4.w;
        uint2 o;
        o.x = f2bf(h0) | (f2bf(h1) << 16);
        o.y = f2bf(h2) | (f2bf(h3) << 16);
        h[i4] = o;
    }
}

// ---- single-block scan: bucket totals -> bstart prefix -> per-(bucket,block) bbase ----
__global__ __launch_bounds__(1024) void scan_kernel(const int* __restrict__ bhist,
                                                    int* __restrict__ bstart,
                                                    int* __restrict__ bbase) {
    __shared__ int sm[1024];
    __shared__ int ex[1024];
    int t = threadIdx.x;
    int wave = t >> 6, lane = t & 63;
    sm[t] = 0;
    __syncthreads();
    // phase A: per-bucket totals (coalesced rows of transposed bhist)
    for (int wv = wave; wv < NBUCK; wv += 16) {
        int s = 0;
        for (int idx = lane; idx < NBLK; idx += 64) s += bhist[(size_t)wv * NBLK + idx];
        for (int d = 32; d > 0; d >>= 1) s += __shfl_down(s, d);
        if (lane == 0) sm[wv] = s;
    }
    __syncthreads();
    int v = sm[t];
    // phase B: block scan (inclusive) -> exclusive starts
    for (int off = 1; off < 1024; off <<= 1) {
        int xv = (t >= off) ? sm[t - off] : 0;
        __syncthreads();
        sm[t] += xv;
        __syncthreads();
    }
    ex[t] = sm[t] - v;
    if (t < NBUCK) bstart[t] = sm[t] - v;
    if (t == 0) bstart[NBUCK] = sm[1023];   // == N_EDGES
    __syncthreads();
    // phase C: per-bucket prefix over the 196 block counts
    for (int wv = wave; wv < NBUCK; wv += 16) {
        int base = ex[wv];
        int carry = 0;
#pragma unroll
        for (int seg = 0; seg < NSEG; ++seg) {
            int idx = seg * 64 + lane;
            int vv = (idx < NBLK) ? bhist[(size_t)wv * NBLK + idx] : 0;
            int s = vv;
            for (int d = 1; d < 64; d <<= 1) {
                int u = __shfl_up(s, d);
                if (lane >= d) s += u;
            }
            if (idx < NBLK) bbase[(size_t)wv * NBLK + idx] = base + carry + s - vv;
            carry += __shfl(s, 63);
        }
    }
}

// ---- sort pass 2: scatter into bucket-sorted staging, LDS cursors only ----
__global__ __launch_bounds__(1024) void sort2_kernel(
        const int* __restrict__ rows, const int* __restrict__ cols,
        const float* __restrict__ vals, const int* __restrict__ rels,
        const float* __restrict__ relc, const int* __restrict__ bbase,
        uint2* __restrict__ staging) {
    __shared__ int lcur[NBUCK];
    __shared__ float lrel[NREL];
    int t = threadIdx.x, b = blockIdx.x;
    if (t < NREL) lrel[t] = 1.0f / (relc[t] + 1.0f);
    for (int i = t; i < NBUCK; i += 1024) lcur[i] = bbase[(size_t)i * NBLK + b];
    __syncthreads();
    int e0 = b * EPB, e1 = min(e0 + EPB, N_EDGES);
    for (int e = e0 + t; e < e1; e += 1024) {
        int r = rows[e];
        float w = vals[e] * lrel[rels[e]];
        int p = atomicAdd(&lcur[r >> 7], 1);
        uint2 s;
        s.x = (uint32_t)cols[e] | ((uint32_t)(r & 127) << 20);  // col<2^17, rowlocal<128
        s.y = __float_as_uint(w);
        staging[p] = s;
    }
}

// ---- per-bucket: LDS row histogram -> padded scan -> rowrange + reorder + zero-pads ----
__global__ __launch_bounds__(256) void bucket_kernel(
        const uint2* __restrict__ staging, const int* __restrict__ bstart,
        uint2* __restrict__ rowrange, uint2* __restrict__ scolw) {
    __shared__ int lh[128];
    __shared__ int sm[128];
    __shared__ int lcur[128];
    int b = blockIdx.x, r0 = b << 7, t = threadIdx.x;
    int nrows = min(128, N_NODES - r0);
    if (t < 128) lh[t] = 0;
    __syncthreads();
    int e0 = bstart[b], e1 = bstart[b + 1];
    for (int e = e0 + t; e < e1; e += 256)
        atomicAdd(&lh[(staging[e].x >> 20) & 127], 1);
    __syncthreads();
    int v = (t < 128) ? lh[t] : 0;
    int pv = (v + 3) & ~3;               // pad each row to multiple of 4
    if (t < 128) sm[t] = pv;
    __syncthreads();
    for (int off = 1; off < 128; off <<= 1) {
        int xv = 0;
        if (t < 128 && t >= off) xv = sm[t - off];
        __syncthreads();
        if (t < 128) sm[t] += xv;
        __syncthreads();
    }
    int sbase = e0 + SLACK * b;          // padded region base in scolw
    int start = 0;
    if (t < 128) {
        start = sbase + sm[t] - pv;      // exclusive padded offset
        lcur[t] = start;
        if (t < nrows) {
            uint2 rr; rr.x = (uint32_t)start; rr.y = (uint32_t)(start + pv);
            rowrange[r0 + t] = rr;
        }
    }
    __syncthreads();
    for (int e = e0 + t; e < e1; e += 256) {
        uint2 s = staging[e];
        int rl = (s.x >> 20) & 127;
        int p = atomicAdd(&lcur[rl], 1);
        uint2 o; o.x = s.x & 0xFFFFF; o.y = s.y;
        scolw[p] = o;
    }
    // zero-weight pads: region [start+v, start+pv) disjoint from reorder writes
    if (t < 128) {
        uint2 z; z.x = 0; z.y = 0;
        for (int k = v; k < pv; ++k) scolw[start + k] = z;
    }
}

// ---- pull SpMM + diag: exact 4-edge steps, uniform edge loads, no shuffles ----
__global__ __launch_bounds__(256) void spmm_kernel(
        const uint32_t* __restrict__ h, const uint2* __restrict__ rowrange,
        const uint2* __restrict__ scolw, const float* __restrict__ ck,
        uint32_t* __restrict__ pre) {
    int row = blockIdx.x * 4 + (threadIdx.x >> 6);
    int lane = threadIdx.x & 63;
    uint2 rr = rowrange[row];
    int e  = __builtin_amdgcn_readfirstlane((int)rr.x);
    int e1 = __builtin_amdgcn_readfirstlane((int)rr.y);
    uint32_t p = h[(size_t)row * 64 + lane];
    float coef = ck[row] + 1.0f;
    float ax = coef * bflo(p);
    float ay = coef * bfhi(p);
    for (; e < e1; e += 4) {
        const uint4* ep = (const uint4*)(scolw + e);   // 16B-aligned: e % 4 == 0
        uint4 eA = ep[0];   // edges e, e+1
        uint4 eB = ep[1];   // edges e+2, e+3
        uint32_t q0 = h[eA.x * 64u + lane];
        uint32_t q1 = h[eA.z * 64u + lane];
        uint32_t q2 = h[eB.x * 64u + lane];
        uint32_t q3 = h[eB.z * 64u + lane];
        float w0 = __uint_as_float(eA.y), w1 = __uint_as_float(eA.w);
        float w2 = __uint_as_float(eB.y), w3 = __uint_as_float(eB.w);
        ax += w0 * bflo(q0); ay += w0 * bfhi(q0);
        ax += w1 * bflo(q1); ay += w1 * bfhi(q1);
        ax += w2 * bflo(q2); ay += w2 * bfhi(q2);
        ax += w3 * bflo(q3); ay += w3 * bfhi(q3);
    }
    pre[(size_t)row * 64 + lane] = f2bf(ax) | (f2bf(ay) << 16);
}

// ---- out = pre @ W + bias via MFMA bf16 16x16x32 ----
__global__ __launch_bounds__(256) void gemm_kernel(
        const uint16_t* __restrict__ pre, const uint16_t* __restrict__ WT,
        const float* __restrict__ bias, float* __restrict__ out) {
    int wave = threadIdx.x >> 6;
    int lane = threadIdx.x & 63;
    int row0 = blockIdx.x * 64 + wave * 16;
    int m = lane & 15, q = lane >> 4;

    short8_t a[4];
    const uint16_t* arow = pre + (size_t)(row0 + m) * FDIM + q * 8;
#pragma unroll
    for (int t = 0; t < 4; ++t)
        a[t] = *(const short8_t*)(arow + t * 32);

    for (int ct = 0; ct < 8; ++ct) {
        int col0 = ct * 16;
        const uint16_t* brow = WT + (size_t)(col0 + m) * FDIM + q * 8;
        f32x4_t acc = {0.f, 0.f, 0.f, 0.f};
#pragma unroll
        for (int t = 0; t < 4; ++t) {
            short8_t b = *(const short8_t*)(brow + t * 32);
            acc = __builtin_amdgcn_mfma_f32_16x16x32_bf16(a[t], b, acc, 0, 0, 0);
        }
        float bs = bias[col0 + m];
#pragma unroll
        for (int r = 0; r < 4; ++r) {
            int row = row0 + q * 4 + r;
            if (row < N_NODES)
                out[(size_t)row * FDIM + col0 + m] = acc[r] + bs;
        }
    }
}

extern "C" void kernel_launch(void* const* d_in, const int* in_sizes, int n_in,
                              void* d_out, int out_size, void* d_ws, size_t ws_size,
                              hipStream_t stream) {
    const float* x     = (const float*)d_in[0];
    const int*   erows = (const int*)d_in[1];
    const int*   ecols = (const int*)d_in[2];
    const float* evals = (const float*)d_in[3];
    const int*   erels = (const int*)d_in[4];
    const float* relc  = (const float*)d_in[5];
    const float* ck    = (const float*)d_in[6];
    const float* W     = (const float*)d_in[7];
    const float* bias  = (const float*)d_in[8];
    const float* gamma = (const float*)d_in[9];
    const float* beta  = (const float*)d_in[10];
    const float* mean  = (const float*)d_in[11];
    const float* var   = (const float*)d_in[12];
    float* out = (float*)d_out;

    char* wp = (char*)d_ws;
    auto alloc = [&](size_t bytes) {
        char* p = wp;
        wp += (bytes + 255) & ~(size_t)255;
        return (void*)p;
    };
    uint16_t* h      = (uint16_t*)alloc((size_t)N_PAD * FDIM * 2);
    uint16_t* pre    = (uint16_t*)alloc((size_t)N_PAD * FDIM * 2);  // staging aliased below
    uint2* scolw     = (uint2*)alloc((size_t)(N_EDGES + SLACK * NBUCK) * 8);
    uint2* rowrange  = (uint2*)alloc((size_t)N_NODES * 8);
    int* bhist       = (int*)alloc((size_t)NBUCK * NBLK * 4);
    int* bbase       = (int*)alloc((size_t)NBUCK * NBLK * 4);
    int* bstart      = (int*)alloc((size_t)(NBUCK + 1) * 4);
    uint16_t* WT     = (uint16_t*)alloc(FDIM * FDIM * 2);
    if ((size_t)(wp - (char*)d_ws) > ws_size) return;

    uint2* staging = (uint2*)pre;   // 12.8MB inside pre's 25.6MB; dead before spmm writes pre

    pre_kernel<<<NBLK + 1 + HBLK, 512, 0, stream>>>(x, erows, gamma, beta, mean, var, W,
                                                    (uint2*)h, bhist, WT);
    scan_kernel<<<1, 1024, 0, stream>>>(bhist, bstart, bbase);
    sort2_kernel<<<NBLK, 1024, 0, stream>>>(erows, ecols, evals, erels, relc, bbase, staging);
    bucket_kernel<<<NBUCK, 256, 0, stream>>>(staging, bstart, rowrange, scolw);
    spmm_kernel<<<N_NODES / 4, 256, 0, stream>>>((const uint32_t*)h, rowrange, scolw, ck,
                                                 (uint32_t*)pre);
    gemm_kernel<<<(N_NODES + 63) / 64, 256, 0, stream>>>(pre, WT, bias, out);
}

// Round 7
// 287.294 us; speedup vs baseline: 1.3978x; 1.3978x over previous
//
#include <hip/hip_runtime.h>
#include <stdint.h>

#define N_NODES 100000
#define N_EDGES 1600000
#define FDIM 128
#define NREL 50
#define BN_EPS 1e-3f
#define N_PAD 100096
#define NBUCK 782          // ceil(N_NODES / 128)
#define EPB 8192           // edges per sort block
#define NBLK 196           // ceil(N_EDGES / EPB)
#define NSEG 4             // ceil(NBLK / 64)
#define SLACK 384          // max pad per bucket: 128 rows * 3
#define HBLK 6250          // N*32 / 512

typedef short short8_t __attribute__((ext_vector_type(8)));
typedef float f32x4_t __attribute__((ext_vector_type(4)));

__device__ __forceinline__ uint32_t f2bf(float f) {
    union { float f; uint32_t u; } v; v.f = f;
    uint32_t u = v.u;
    return (u + 0x7FFFu + ((u >> 16) & 1u)) >> 16;   // RNE, inputs finite
}
__device__ __forceinline__ float bflo(uint32_t p) {
    union { uint32_t u; float f; } v; v.u = p << 16; return v.f;
}
__device__ __forceinline__ float bfhi(uint32_t p) {
    union { uint32_t u; float f; } v; v.u = p & 0xFFFF0000u; return v.f;
}

// ---- fused prologue: blocks [0,NBLK) = bucket histogram; block NBLK = WT cast;
// blocks (NBLK, NBLK+HBLK] = BN h (per-thread scale/shift, params L2-hot).
__global__ __launch_bounds__(512) void pre_kernel(
        const float* __restrict__ x, const int* __restrict__ rows,
        const float* __restrict__ gamma, const float* __restrict__ beta,
        const float* __restrict__ mean, const float* __restrict__ var,
        const float* __restrict__ W,
        uint2* __restrict__ h, int* __restrict__ bhist, uint16_t* __restrict__ WT) {
    __shared__ int lh[NBUCK];
    int b = blockIdx.x, t = threadIdx.x;
    if (b < NBLK) {
        for (int i = t; i < NBUCK; i += 512) lh[i] = 0;
        __syncthreads();
        int e0 = b * EPB, e1 = min(e0 + EPB, N_EDGES);
        for (int e = e0 + t; e < e1; e += 512)
            atomicAdd(&lh[rows[e] >> 7], 1);
        __syncthreads();
        for (int i = t; i < NBUCK; i += 512) bhist[(size_t)i * NBLK + b] = lh[i];
    } else if (b == NBLK) {
        for (int idx = t; idx < FDIM * FDIM; idx += 512) {
            int f = idx >> 7, k = idx & 127;
            WT[idx] = (uint16_t)f2bf(W[k * FDIM + f]);   // WT[f][k]
        }
    } else {
        int i4 = (b - NBLK - 1) * 512 + t;     // 0 .. N*32-1 exactly
        int cg = (i4 & 31) * 4;
        float4 xv = ((const float4*)x)[i4];
        float4 g4 = *(const float4*)(gamma + cg);
        float4 b4 = *(const float4*)(beta + cg);
        float4 m4 = *(const float4*)(mean + cg);
        float4 v4 = *(const float4*)(var + cg);
        float s0 = g4.x * rsqrtf(v4.x + BN_EPS);
        float s1 = g4.y * rsqrtf(v4.y + BN_EPS);
        float s2 = g4.z * rsqrtf(v4.z + BN_EPS);
        float s3 = g4.w * rsqrtf(v4.w + BN_EPS);
        uint2 o;
        o.x = f2bf((xv.x - m4.x) * s0 + b4.x) | (f2bf((xv.y - m4.y) * s1 + b4.y) << 16);
        o.y = f2bf((xv.z - m4.z) * s2 + b4.z) | (f2bf((xv.w - m4.w) * s3 + b4.w) << 16);
        h[i4] = o;
    }
}

// ---- per-bucket total: one wave per bucket, coalesced (transposed bhist) ----
__global__ __launch_bounds__(256) void btot_kernel(const int* __restrict__ bhist,
                                                   int* __restrict__ btot) {
    int wv = (blockIdx.x * 256 + threadIdx.x) >> 6;
    int lane = threadIdx.x & 63;
    if (wv >= NBUCK) return;
    int s = 0;
    for (int idx = lane; idx < NBLK; idx += 64) s += bhist[(size_t)wv * NBLK + idx];
    for (int d = 32; d > 0; d >>= 1) s += __shfl_down(s, d);
    if (lane == 0) btot[wv] = s;
}

// ---- bucket prefix: single block scans 782 totals -> bstart (exclusive) ----
__global__ __launch_bounds__(1024) void bprefix_kernel(const int* __restrict__ btot,
                                                       int* __restrict__ bstart) {
    __shared__ int sm[1024];
    int t = threadIdx.x;
    int v = (t < NBUCK) ? btot[t] : 0;
    sm[t] = v;
    __syncthreads();
    for (int off = 1; off < 1024; off <<= 1) {
        int xv = (t >= off) ? sm[t - off] : 0;
        __syncthreads();
        sm[t] += xv;
        __syncthreads();
    }
    if (t < NBUCK) bstart[t] = sm[t] - v;   // exclusive
    if (t == 0) bstart[NBUCK] = sm[1023];   // == N_EDGES
}

// ---- per-(bucket,block) base: one wave per bucket, coalesced ----
__global__ __launch_bounds__(256) void bscan_kernel(const int* __restrict__ bhist,
                                                    const int* __restrict__ bstart,
                                                    int* __restrict__ bbase) {
    int wv = (blockIdx.x * 256 + threadIdx.x) >> 6;
    int lane = threadIdx.x & 63;
    if (wv >= NBUCK) return;
    int base = bstart[wv];
    int carry = 0;
#pragma unroll
    for (int seg = 0; seg < NSEG; ++seg) {
        int idx = seg * 64 + lane;
        int v = (idx < NBLK) ? bhist[(size_t)wv * NBLK + idx] : 0;
        int s = v;
        for (int d = 1; d < 64; d <<= 1) {
            int u = __shfl_up(s, d);
            if (lane >= d) s += u;
        }
        if (idx < NBLK) bbase[(size_t)wv * NBLK + idx] = base + carry + s - v;
        carry += __shfl(s, 63);
    }
}

// ---- sort pass 2: scatter into bucket-sorted staging, LDS cursors only ----
__global__ __launch_bounds__(1024) void sort2_kernel(
        const int* __restrict__ rows, const int* __restrict__ cols,
        const float* __restrict__ vals, const int* __restrict__ rels,
        const float* __restrict__ relc, const int* __restrict__ bbase,
        uint2* __restrict__ staging) {
    __shared__ int lcur[NBUCK];
    __shared__ float lrel[NREL];
    int t = threadIdx.x, b = blockIdx.x;
    if (t < NREL) lrel[t] = 1.0f / (relc[t] + 1.0f);
    for (int i = t; i < NBUCK; i += 1024) lcur[i] = bbase[(size_t)i * NBLK + b];
    __syncthreads();
    int e0 = b * EPB, e1 = min(e0 + EPB, N_EDGES);
    for (int e = e0 + t; e < e1; e += 1024) {
        int r = rows[e];
        float w = vals[e] * lrel[rels[e]];
        int p = atomicAdd(&lcur[r >> 7], 1);
        uint2 s;
        s.x = (uint32_t)cols[e] | ((uint32_t)(r & 127) << 20);  // col<2^17, rowlocal<128
        s.y = __float_as_uint(w);
        staging[p] = s;
    }
}

// ---- per-bucket: LDS row histogram -> padded scan -> rowrange + reorder + zero-pads ----
__global__ __launch_bounds__(256) void bucket_kernel(
        const uint2* __restrict__ staging, const int* __restrict__ bstart,
        uint2* __restrict__ rowrange, uint2* __restrict__ scolw) {
    __shared__ int lh[128];
    __shared__ int sm[128];
    __shared__ int lcur[128];
    int b = blockIdx.x, r0 = b << 7, t = threadIdx.x;
    int nrows = min(128, N_NODES - r0);
    if (t < 128) lh[t] = 0;
    __syncthreads();
    int e0 = bstart[b], e1 = bstart[b + 1];
    for (int e = e0 + t; e < e1; e += 256)
        atomicAdd(&lh[(staging[e].x >> 20) & 127], 1);
    __syncthreads();
    int v = (t < 128) ? lh[t] : 0;
    int pv = (v + 3) & ~3;               // pad each row to multiple of 4
    if (t < 128) sm[t] = pv;
    __syncthreads();
    for (int off = 1; off < 128; off <<= 1) {
        int xv = 0;
        if (t < 128 && t >= off) xv = sm[t - off];
        __syncthreads();
        if (t < 128) sm[t] += xv;
        __syncthreads();
    }
    int sbase = e0 + SLACK * b;          // padded region base in scolw
    int start = 0;
    if (t < 128) {
        start = sbase + sm[t] - pv;      // exclusive padded offset
        lcur[t] = start;
        if (t < nrows) {
            uint2 rr; rr.x = (uint32_t)start; rr.y = (uint32_t)(start + pv);
            rowrange[r0 + t] = rr;
        }
    }
    __syncthreads();
    for (int e = e0 + t; e < e1; e += 256) {
        uint2 s = staging[e];
        int rl = (s.x >> 20) & 127;
        int p = atomicAdd(&lcur[rl], 1);
        uint2 o; o.x = s.x & 0xFFFFF; o.y = s.y;
        scolw[p] = o;
    }
    // zero-weight pads: region [start+v, start+pv) disjoint from reorder writes
    if (t < 128) {
        uint2 z; z.x = 0; z.y = 0;
        for (int k = v; k < pv; ++k) scolw[start + k] = z;
    }
}

// ---- pull SpMM + diag: exact 4-edge steps, uniform edge loads, no shuffles ----
__global__ __launch_bounds__(256) void spmm_kernel(
        const uint32_t* __restrict__ h, const uint2* __restrict__ rowrange,
        const uint2* __restrict__ scolw, const float* __restrict__ ck,
        uint32_t* __restrict__ pre) {
    int row = blockIdx.x * 4 + (threadIdx.x >> 6);
    int lane = threadIdx.x & 63;
    uint2 rr = rowrange[row];
    int e  = __builtin_amdgcn_readfirstlane((int)rr.x);
    int e1 = __builtin_amdgcn_readfirstlane((int)rr.y);
    uint32_t p = h[(size_t)row * 64 + lane];
    float coef = ck[row] + 1.0f;
    float ax = coef * bflo(p);
    float ay = coef * bfhi(p);
    for (; e < e1; e += 4) {
        const uint4* ep = (const uint4*)(scolw + e);   // 16B-aligned: e % 4 == 0
        uint4 eA = ep[0];   // edges e, e+1
        uint4 eB = ep[1];   // edges e+2, e+3
        uint32_t q0 = h[eA.x * 64u + lane];
        uint32_t q1 = h[eA.z * 64u + lane];
        uint32_t q2 = h[eB.x * 64u + lane];
        uint32_t q3 = h[eB.z * 64u + lane];
        float w0 = __uint_as_float(eA.y), w1 = __uint_as_float(eA.w);
        float w2 = __uint_as_float(eB.y), w3 = __uint_as_float(eB.w);
        ax += w0 * bflo(q0); ay += w0 * bfhi(q0);
        ax += w1 * bflo(q1); ay += w1 * bfhi(q1);
        ax += w2 * bflo(q2); ay += w2 * bfhi(q2);
        ax += w3 * bflo(q3); ay += w3 * bfhi(q3);
    }
    pre[(size_t)row * 64 + lane] = f2bf(ax) | (f2bf(ay) << 16);
}

// ---- out = pre @ W + bias via MFMA bf16 16x16x32 ----
__global__ __launch_bounds__(256) void gemm_kernel(
        const uint16_t* __restrict__ pre, const uint16_t* __restrict__ WT,
        const float* __restrict__ bias, float* __restrict__ out) {
    int wave = threadIdx.x >> 6;
    int lane = threadIdx.x & 63;
    int row0 = blockIdx.x * 64 + wave * 16;
    int m = lane & 15, q = lane >> 4;

    short8_t a[4];
    const uint16_t* arow = pre + (size_t)(row0 + m) * FDIM + q * 8;
#pragma unroll
    for (int t = 0; t < 4; ++t)
        a[t] = *(const short8_t*)(arow + t * 32);

    for (int ct = 0; ct < 8; ++ct) {
        int col0 = ct * 16;
        const uint16_t* brow = WT + (size_t)(col0 + m) * FDIM + q * 8;
        f32x4_t acc = {0.f, 0.f, 0.f, 0.f};
#pragma unroll
        for (int t = 0; t < 4; ++t) {
            short8_t b = *(const short8_t*)(brow + t * 32);
            acc = __builtin_amdgcn_mfma_f32_16x16x32_bf16(a[t], b, acc, 0, 0, 0);
        }
        float bs = bias[col0 + m];
#pragma unroll
        for (int r = 0; r < 4; ++r) {
            int row = row0 + q * 4 + r;
            if (row < N_NODES)
                out[(size_t)row * FDIM + col0 + m] = acc[r] + bs;
        }
    }
}

extern "C" void kernel_launch(void* const* d_in, const int* in_sizes, int n_in,
                              void* d_out, int out_size, void* d_ws, size_t ws_size,
                              hipStream_t stream) {
    const float* x     = (const float*)d_in[0];
    const int*   erows = (const int*)d_in[1];
    const int*   ecols = (const int*)d_in[2];
    const float* evals = (const float*)d_in[3];
    const int*   erels = (const int*)d_in[4];
    const float* relc  = (const float*)d_in[5];
    const float* ck    = (const float*)d_in[6];
    const float* W     = (const float*)d_in[7];
    const float* bias  = (const float*)d_in[8];
    const float* gamma = (const float*)d_in[9];
    const float* beta  = (const float*)d_in[10];
    const float* mean  = (const float*)d_in[11];
    const float* var   = (const float*)d_in[12];
    float* out = (float*)d_out;

    char* wp = (char*)d_ws;
    auto alloc = [&](size_t bytes) {
        char* p = wp;
        wp += (bytes + 255) & ~(size_t)255;
        return (void*)p;
    };
    uint16_t* h      = (uint16_t*)alloc((size_t)N_PAD * FDIM * 2);
    uint16_t* pre    = (uint16_t*)alloc((size_t)N_PAD * FDIM * 2);  // staging aliased below
    uint2* scolw     = (uint2*)alloc((size_t)(N_EDGES + SLACK * NBUCK) * 8);
    uint2* rowrange  = (uint2*)alloc((size_t)N_NODES * 8);
    int* bhist       = (int*)alloc((size_t)NBUCK * NBLK * 4);
    int* bbase       = (int*)alloc((size_t)NBUCK * NBLK * 4);
    int* btot        = (int*)alloc((size_t)NBUCK * 4);
    int* bstart      = (int*)alloc((size_t)(NBUCK + 1) * 4);
    uint16_t* WT     = (uint16_t*)alloc(FDIM * FDIM * 2);
    if ((size_t)(wp - (char*)d_ws) > ws_size) return;

    uint2* staging = (uint2*)pre;   // 12.8MB inside pre's 25.6MB; dead before spmm writes pre

    pre_kernel<<<NBLK + 1 + HBLK, 512, 0, stream>>>(x, erows, gamma, beta, mean, var, W,
                                                    (uint2*)h, bhist, WT);
    btot_kernel<<<(NBUCK + 3) / 4, 256, 0, stream>>>(bhist, btot);
    bprefix_kernel<<<1, 1024, 0, stream>>>(btot, bstart);
    bscan_kernel<<<(NBUCK + 3) / 4, 256, 0, stream>>>(bhist, bstart, bbase);
    sort2_kernel<<<NBLK, 1024, 0, stream>>>(erows, ecols, evals, erels, relc, bbase, staging);
    bucket_kernel<<<NBUCK, 256, 0, stream>>>(staging, bstart, rowrange, scolw);
    spmm_kernel<<<N_NODES / 4, 256, 0, stream>>>((const uint32_t*)h, rowrange, scolw, ck,
                                                 (uint32_t*)pre);
    gemm_kernel<<<(N_NODES + 63) / 64, 256, 0, stream>>>(pre, WT, bias, out);
}